// Round 4
// baseline (171.456 us; speedup 1.0000x reference)
//
#include <hip/hip_runtime.h>

// B=16, K=32, H=W=28, HID=OUT=64, NOPS=8
// ws layout: h1 f32[512*6272] | h2b bf16[512*3136] | feat f32[512*64] | s[16*64]
//            t7c[16*64] | x8[16*64] | Wt f32[8*64*64] ([m][e][d]) | fcwb bf16[64*3136]

typedef __attribute__((ext_vector_type(8))) short short8;
typedef __attribute__((ext_vector_type(4))) float f32x4;

__device__ __forceinline__ f32x4 mfma_bf16(short8 a, short8 b, f32x4 c) {
  return __builtin_amdgcn_mfma_f32_16x16x32_bf16(a, b, c, 0, 0, 0);
}

// float -> bf16 bits, round-to-nearest-even (finite inputs only)
__device__ __forceinline__ unsigned short f2bs(float f) {
  unsigned int u = __float_as_uint(f);
  unsigned int r = u + 0x7fffu + ((u >> 16) & 1u);
  return (unsigned short)(r >> 16);
}
__device__ __forceinline__ unsigned int pk2(float x, float y) {
  return (unsigned int)f2bs(x) | ((unsigned int)f2bs(y) << 16);
}
__device__ __forceinline__ void stb4(short* p, float4 v) {
  *(unsigned int*)(p)     = pk2(v.x, v.y);
  *(unsigned int*)(p + 2) = pk2(v.z, v.w);
}

// ---------------- k1: conv1 + ReLU + maxpool2, blocks >=512 do weight prep ----------------
__global__ __launch_bounds__(256) void k1_conv1(const float* __restrict__ x,
    const float* __restrict__ w, const float* __restrict__ bias,
    float* __restrict__ h1,
    const float* __restrict__ eqw, float* __restrict__ Wt,
    const float* __restrict__ fcw, short* __restrict__ fcwb) {
  const int n = blockIdx.x, t = threadIdx.x;
  if (n >= 512) {
    if (n < 520) {               // eq_w (d,e,m) -> Wt[m][e][d]
      const int m = n - 512;
      for (int idx = t; idx < 4096; idx += 256) {
        int e = idx >> 6, d = idx & 63;
        Wt[m*4096 + idx] = eqw[d*512 + e*8 + m];
      }
    } else {                     // fc_w f32 -> bf16 (same [e][k] layout)
      int base = (n - 520)*12544 + t;
      for (int q = 0; q < 49; ++q) {
        int idx = base + q*256;
        fcwb[idx] = (short)f2bs(fcw[idx]);
      }
    }
    return;
  }
  __shared__ float si[30*30];
  __shared__ float sw[32*9];
  __shared__ float sb[32];
  for (int idx = t; idx < 900; idx += 256) si[idx] = 0.f;
  for (int idx = t; idx < 288; idx += 256) sw[idx] = w[idx];
  if (t < 32) sb[t] = bias[t];
  __syncthreads();
  for (int idx = t; idx < 784; idx += 256) {
    int y = idx / 28, xx = idx - y*28;
    si[(y+1)*30 + xx + 1] = x[n*784 + idx];
  }
  __syncthreads();
  for (int item = t; item < 6272; item += 256) {
    int c = item / 196, rem = item - c*196;
    int py = rem / 14, px = rem - py*14;
    float pt[4][4];
#pragma unroll
    for (int r = 0; r < 4; ++r)
#pragma unroll
      for (int q = 0; q < 4; ++q)
        pt[r][q] = si[(2*py + r)*30 + 2*px + q];
    const float* wc = &sw[c*9];
    float w0=wc[0], w1=wc[1], w2=wc[2], w3=wc[3], w4=wc[4], w5=wc[5], w6=wc[6], w7=wc[7], w8=wc[8];
    float bb = sb[c];
    float best = 0.f;
#pragma unroll
    for (int a = 0; a < 2; ++a)
#pragma unroll
      for (int b2 = 0; b2 < 2; ++b2) {
        float v = bb
          + w0*pt[a+0][b2+0] + w1*pt[a+0][b2+1] + w2*pt[a+0][b2+2]
          + w3*pt[a+1][b2+0] + w4*pt[a+1][b2+1] + w5*pt[a+1][b2+2]
          + w6*pt[a+2][b2+0] + w7*pt[a+2][b2+1] + w8*pt[a+2][b2+2];
        best = fmaxf(best, v);
      }
    h1[n*6272 + item] = best;
  }
}

// ---------------- k2: conv2 via bf16 MFMA implicit-GEMM, writes h2 as bf16 ----------------
__global__ __launch_bounds__(256, 2) void k2_mfma(const float* __restrict__ h1,
    const float* __restrict__ w, const float* __restrict__ bias,
    short* __restrict__ h2b) {
  __shared__ __align__(16) short inT[16*18*40];  // [yy][xx][cin stride 40]
  const int n = blockIdx.x, t = threadIdx.x;
  const int wv = t >> 6, l = t & 63, quad = l >> 4, col = l & 15;

  unsigned int* zp = (unsigned int*)inT;
  for (int idx = t; idx < 16*18*20; idx += 256) zp[idx] = 0u;

  const int c_out = wv*16 + col;
  float w72[72];
  {
    const float4* src = (const float4*)(w + c_out*288 + quad*72);
#pragma unroll
    for (int q = 0; q < 18; ++q) {
      float4 v = src[q];
      w72[q*4+0] = v.x; w72[q*4+1] = v.y; w72[q*4+2] = v.z; w72[q*4+3] = v.w;
    }
  }
  union SU { short8 v; unsigned int u[4]; };
  short8 Bq[9];
#pragma unroll
  for (int dd = 0; dd < 9; ++dd) {
    SU b;
#pragma unroll
    for (int q = 0; q < 4; ++q)
      b.u[q] = pk2(w72[(2*q)*9 + dd], w72[(2*q+1)*9 + dd]);
    Bq[dd] = b.v;
  }
  const float bb = bias[c_out];
  __syncthreads();

  for (int idx = t; idx < 6272; idx += 256) {
    int c = idx / 196, rem = idx - c*196, y = rem / 14, x = rem - y*14;
    inT[(y+1)*720 + (x+1)*40 + c] = (short)f2bs(h1[n*6272 + idx]);
  }
  __syncthreads();

  for (int p = 0; p < 7; ++p) {
    short8 Ar[4][3];
#pragma unroll
    for (int rr = 0; rr < 4; ++rr)
#pragma unroll
      for (int dx = 0; dx < 3; ++dx)
        Ar[rr][dx] = *(const short8*)&inT[(2*p + rr)*720 + (col + dx)*40 + quad*8];
    f32x4 a0 = {0.f,0.f,0.f,0.f}, a1 = {0.f,0.f,0.f,0.f};
#pragma unroll
    for (int dy = 0; dy < 3; ++dy)
#pragma unroll
      for (int dx = 0; dx < 3; ++dx) {
        a0 = mfma_bf16(Ar[dy][dx],     Bq[dy*3 + dx], a0);
        a1 = mfma_bf16(Ar[dy + 1][dx], Bq[dy*3 + dx], a1);
      }
#pragma unroll
    for (int a = 0; a < 2; ++a) {
      int px = quad*2 + a;
      if (px < 7) {
        float m0 = fmaxf(fmaxf(a0[2*a], a0[2*a + 1]), fmaxf(a1[2*a], a1[2*a + 1]));
        h2b[n*3136 + c_out*49 + p*7 + px] = (short)f2bs(fmaxf(m0 + bb, 0.f));
      }
    }
  }
}

// ---------------- k3: FC 3136->64 + ReLU via bf16 MFMA, no LDS ----------------
// grid 16 blocks x 32 images; wave w: m-tile (w&1), n-tiles (w>>1)*2, +1
__global__ __launch_bounds__(256) void k3_mfma(const short* __restrict__ h2b,
    const short* __restrict__ fcwb, const float* __restrict__ fb,
    float* __restrict__ feat) {
  const int blk = blockIdx.x, t = threadIdx.x;
  const int w = t >> 6, l = t & 63, quad = l >> 4, col = l & 15;
  const int mt = w & 1, nh = w >> 1;
  const int img = blk*32 + mt*16 + col;
  const short* Ap = h2b + img*3136 + quad*8;
  const short* B0 = fcwb + (nh*32 + col)*3136 + quad*8;
  const short* B1 = fcwb + (nh*32 + 16 + col)*3136 + quad*8;
  f32x4 acc0 = {0.f,0.f,0.f,0.f}, acc1 = {0.f,0.f,0.f,0.f};
#pragma unroll 7
  for (int ks = 0; ks < 98; ++ks) {
    short8 A  = *(const short8*)(Ap + ks*32);
    short8 b0 = *(const short8*)(B0 + ks*32);
    short8 b1 = *(const short8*)(B1 + ks*32);
    acc0 = mfma_bf16(A, b0, acc0);
    acc1 = mfma_bf16(A, b1, acc1);
  }
  const int e0 = nh*32 + col, e1 = e0 + 16;
  const int base = blk*32 + mt*16 + quad*4;
  const float fb0 = fb[e0], fb1 = fb[e1];
#pragma unroll
  for (int r = 0; r < 4; ++r) {
    feat[(base + r)*64 + e0] = fmaxf(acc0[r] + fb0, 0.f);
    feat[(base + r)*64 + e1] = fmaxf(acc1[r] + fb1, 0.f);
  }
}

// ---------------- k4b: s[b,d], t7c[b,e] = s^3 W7 + eq_b, zero x8 ----------------
__global__ __launch_bounds__(64) void k4_prep(const float* __restrict__ feat,
    const float* __restrict__ Wt, const float* __restrict__ eqb,
    float* __restrict__ s, float* __restrict__ t7c, float* __restrict__ x8) {
  __shared__ float ss[64];
  const int b = blockIdx.x, t = threadIdx.x;
  float a = 0.f;
  for (int i = 0; i < 32; ++i) a += feat[(b*32 + i)*64 + t];
  a *= (1.f/32.f);
  s[b*64 + t] = a;
  ss[t] = a;
  __syncthreads();
  const float* W7 = Wt + 7*4096 + t*64;   // [m=7][e=t][d]
  float t7 = 0.f;
  for (int d = 0; d < 64; ++d) {
    float sv = ss[d];
    t7 += sv*sv*sv * W7[d];
  }
  t7c[b*64 + t] = t7 + eqb[t];
  x8[b*64 + t] = 0.f;
}

// ---------------- k5: fused equivariant layer via bf16 MFMA ----------------
__global__ __launch_bounds__(256, 2) void k5_mfma(const float* __restrict__ feat,
    const float* __restrict__ s_, const float* __restrict__ Wt,
    const float* __restrict__ t7c, float* __restrict__ x8) {
  __shared__ __align__(16) float Fm[32*68];
  __shared__ __align__(16) float FI[64];
  __shared__ __align__(16) float SV[64];
  __shared__ __align__(16) float C0[64];
  __shared__ float C0P[128];
  __shared__ float KCf[32*68];
  __shared__ float JCf[32*68];
  __shared__ float RED[256];
  __shared__ __align__(16) short Fb[32*72];
  __shared__ __align__(16) short QPb[64*72];
  __shared__ __align__(16) short G2b[64*72];
  __shared__ __align__(16) short G3b[64*72];

  const int i = blockIdx.x, b = blockIdx.y, t = threadIdx.x;
  const int w = t >> 6, l = t & 63, quad = l >> 4, col = l & 15;

  for (int idx = t; idx < 2048; idx += 256) {
    int r = idx >> 6, d = idx & 63;
    float v = feat[b*2048 + idx];
    Fm[r*68 + d] = v;
    Fb[r*72 + d] = (short)f2bs(v);
  }
  if (t < 64) { FI[t] = feat[b*2048 + i*64 + t]; SV[t] = s_[b*64 + t]; }
  __syncthreads();

  {
    const int e = t >> 2, dbase = (t & 3) * 16;
    const float* W0 = Wt + 0*4096 + e*64;
    const float* W1 = Wt + 1*4096 + e*64;
    const float* W2 = Wt + 2*4096 + e*64;
    const float* W3 = Wt + 3*4096 + e*64;
    const float* W4 = Wt + 4*4096 + e*64;
    const float* W5 = Wt + 5*4096 + e*64;
#pragma unroll
    for (int q = 0; q < 4; ++q) {
      int off = dbase + q*4;
      float4 fi4 = *(const float4*)&FI[off];
      float4 sv4 = *(const float4*)&SV[off];
      float4 w0 = *(const float4*)&W0[off];
      float4 w1 = *(const float4*)&W1[off];
      float4 w2 = *(const float4*)&W2[off];
      float4 w3 = *(const float4*)&W3[off];
      float4 w4 = *(const float4*)&W4[off];
      float4 w5 = *(const float4*)&W5[off];
      float4 qp = fi4*w0 + sv4*w1;
      float4 g2 = sv4*(fi4*w2 + sv4*w4);
      float4 g3 = sv4*(fi4*w3 + sv4*w5);
      stb4(&QPb[e*72 + off], qp);
      stb4(&G2b[e*72 + off], g2);
      stb4(&G3b[e*72 + off], g3);
    }
  }
  if (t < 128) {
    int e = t & 63, dh = t >> 6;
    const float* W6 = Wt + 6*4096 + e*64 + dh*32;
    const float* fip = FI + dh*32;
    const float* svp = SV + dh*32;
    float a = 0.f;
#pragma unroll
    for (int dd = 0; dd < 32; ++dd) {
      float sd = svp[dd];
      a += sd*sd*fip[dd]*W6[dd];
    }
    C0P[dh*64 + e] = a;
  }
  __syncthreads();

  if (w < 2) {
    const short* G = w ? G3b : G2b;
    float* DST = w ? JCf : KCf;
    short8 Bf[4][2];
#pragma unroll
    for (int n = 0; n < 4; ++n)
#pragma unroll
      for (int s2 = 0; s2 < 2; ++s2)
        Bf[n][s2] = *(const short8*)&G[(n*16 + col)*72 + s2*32 + quad*8];
#pragma unroll
    for (int m = 0; m < 2; ++m) {
      short8 A0 = *(const short8*)&Fb[(m*16 + col)*72 + quad*8];
      short8 A1 = *(const short8*)&Fb[(m*16 + col)*72 + 32 + quad*8];
#pragma unroll
      for (int n = 0; n < 4; ++n) {
        f32x4 z = {0.f, 0.f, 0.f, 0.f};
        f32x4 ac = mfma_bf16(A1, Bf[n][1], mfma_bf16(A0, Bf[n][0], z));
#pragma unroll
        for (int r = 0; r < 4; ++r)
          DST[(m*16 + quad*4 + r)*68 + n*16 + col] = ac[r];
      }
    }
  } else if (w == 2) {
    C0[l] = C0P[l] + C0P[64 + l] + t7c[b*64 + l];
  }
  __syncthreads();

  float c0v[4];
#pragma unroll
  for (int n = 0; n < 4; ++n) c0v[n] = C0[n*16 + col];
  float jcq[8][4];
#pragma unroll
  for (int jj = 0; jj < 8; ++jj)
#pragma unroll
    for (int n = 0; n < 4; ++n)
      jcq[jj][n] = JCf[(w*8 + jj)*68 + n*16 + col] + c0v[n];
  float kcv[2][4][4];
#pragma unroll
  for (int kb2 = 0; kb2 < 2; ++kb2)
#pragma unroll
    for (int r = 0; r < 4; ++r)
#pragma unroll
      for (int n = 0; n < 4; ++n)
        kcv[kb2][r][n] = KCf[(kb2*16 + quad*4 + r)*68 + n*16 + col];
  short8 Bq[4][2];
#pragma unroll
  for (int n = 0; n < 4; ++n)
#pragma unroll
    for (int s2 = 0; s2 < 2; ++s2)
      Bq[n][s2] = *(const short8*)&QPb[(n*16 + col)*72 + s2*32 + quad*8];

  float sum[4] = {0.f, 0.f, 0.f, 0.f};
  union SU { short8 v; unsigned int u[4]; };

#pragma unroll
  for (int mi = 0; mi < 16; ++mi) {
    const int jj = mi >> 1, kb2 = mi & 1;
    const float* fj = &Fm[(w*8 + jj)*68 + quad*8];
    const float* fk = &Fm[(kb2*16 + col)*68 + quad*8];
    float4 ja0 = *(const float4*)(fj);
    float4 ja1 = *(const float4*)(fj + 4);
    float4 jb0 = *(const float4*)(fj + 32);
    float4 jb1 = *(const float4*)(fj + 36);
    float4 ka0 = *(const float4*)(fk);
    float4 ka1 = *(const float4*)(fk + 4);
    float4 kb0 = *(const float4*)(fk + 32);
    float4 kb1 = *(const float4*)(fk + 36);
    SU A0, A1;
    A0.u[0] = pk2(ja0.x*ka0.x, ja0.y*ka0.y);
    A0.u[1] = pk2(ja0.z*ka0.z, ja0.w*ka0.w);
    A0.u[2] = pk2(ja1.x*ka1.x, ja1.y*ka1.y);
    A0.u[3] = pk2(ja1.z*ka1.z, ja1.w*ka1.w);
    A1.u[0] = pk2(jb0.x*kb0.x, jb0.y*kb0.y);
    A1.u[1] = pk2(jb0.z*kb0.z, jb0.w*kb0.w);
    A1.u[2] = pk2(jb1.x*kb1.x, jb1.y*kb1.y);
    A1.u[3] = pk2(jb1.z*kb1.z, jb1.w*kb1.w);
    f32x4 ac[4];
#pragma unroll
    for (int n = 0; n < 4; ++n) {
      f32x4 z = {0.f, 0.f, 0.f, 0.f};
      ac[n] = mfma_bf16(A1.v, Bq[n][1], mfma_bf16(A0.v, Bq[n][0], z));
    }
#pragma unroll
    for (int n = 0; n < 4; ++n)
#pragma unroll
      for (int r = 0; r < 4; ++r) {
        float v = ac[n][r] + kcv[kb2][r][n] + jcq[jj][n];
        sum[n] += fmaxf(v, 0.f);
      }
  }

#pragma unroll
  for (int n = 0; n < 4; ++n) {
    float v = sum[n];
    v += __shfl_xor(v, 16, 64);
    v += __shfl_xor(v, 32, 64);
    if (l < 16) RED[w*64 + n*16 + l] = v;
  }
  __syncthreads();
  if (t < 64) {
    float tot = RED[t] + RED[64 + t] + RED[128 + t] + RED[192 + t];
    atomicAdd(&x8[b*64 + t], tot);
  }
}

// ---------------- k6: x9 = relu(x8/K^3); out = x9 @ out_w.T + out_b ----------------
__global__ __launch_bounds__(64) void k6_out(const float* __restrict__ x8,
    const float* __restrict__ ow, const float* __restrict__ ob,
    float* __restrict__ out) {
  const int bb = blockIdx.x, t = threadIdx.x;
  float v = fmaxf(x8[bb*64 + t] * (1.f/32768.f), 0.f) * ow[t];
#pragma unroll
  for (int off = 32; off > 0; off >>= 1) v += __shfl_down(v, off, 64);
  if (t == 0) out[bb] = v + ob[0];
}

extern "C" void kernel_launch(void* const* d_in, const int* in_sizes, int n_in,
                              void* d_out, int out_size, void* d_ws, size_t ws_size,
                              hipStream_t stream) {
  const float* x   = (const float*)d_in[0];
  const float* c1w = (const float*)d_in[1];
  const float* c1b = (const float*)d_in[2];
  const float* c2w = (const float*)d_in[3];
  const float* c2b = (const float*)d_in[4];
  const float* fcw = (const float*)d_in[5];
  const float* fcb = (const float*)d_in[6];
  const float* eqw = (const float*)d_in[7];
  const float* eqb = (const float*)d_in[8];
  const float* ow  = (const float*)d_in[9];
  const float* ob  = (const float*)d_in[10];
  float* out = (float*)d_out;

  float* ws   = (float*)d_ws;
  float* h1   = ws;                       // 512*6272 f32
  short* h2b  = (short*)(h1 + 512*6272);  // 512*3136 bf16
  float* feat = (float*)(h2b + 512*3136); // 512*64 f32
  float* s    = feat + 512*64;            // 16*64
  float* t7c  = s + 1024;
  float* x8   = t7c + 1024;
  float* Wt   = x8 + 1024;                // 8*64*64
  short* fcwb = (short*)(Wt + 32768);     // 64*3136 bf16

  hipLaunchKernelGGL(k1_conv1, dim3(536), dim3(256), 0, stream,
                     x, c1w, c1b, h1, eqw, Wt, fcw, fcwb);
  hipLaunchKernelGGL(k2_mfma,  dim3(512), dim3(256), 0, stream, h1, c2w, c2b, h2b);
  hipLaunchKernelGGL(k3_mfma,  dim3(16),  dim3(256), 0, stream, h2b, fcwb, fcb, feat);
  hipLaunchKernelGGL(k4_prep,  dim3(16),  dim3(64),  0, stream, feat, Wt, eqb, s, t7c, x8);
  hipLaunchKernelGGL(k5_mfma,  dim3(32, 16), dim3(256), 0, stream, feat, s, Wt, t7c, x8);
  hipLaunchKernelGGL(k6_out,   dim3(16),  dim3(64),  0, stream, x8, ow, ob, out);
}

// Round 5
// 137.497 us; speedup vs baseline: 1.2470x; 1.2470x over previous
//
#include <hip/hip_runtime.h>

// B=16, K=32, H=W=28, HID=OUT=64, NOPS=8
// ws layout: h1 f32[512*6272] | h2b bf16[512*3136] | feat f32[512*64] | s[16*64]
//            t7c[16*64] | x8[16*64] | Wt f32[8*64*64] ([m][e][d]) | fcwb bf16[64*3136]
//            | part f32[14*512*64]

typedef __attribute__((ext_vector_type(8))) short short8;
typedef __attribute__((ext_vector_type(4))) float f32x4;

__device__ __forceinline__ f32x4 mfma_bf16(short8 a, short8 b, f32x4 c) {
  return __builtin_amdgcn_mfma_f32_16x16x32_bf16(a, b, c, 0, 0, 0);
}

// float -> bf16 bits, round-to-nearest-even (finite inputs only)
__device__ __forceinline__ unsigned short f2bs(float f) {
  unsigned int u = __float_as_uint(f);
  unsigned int r = u + 0x7fffu + ((u >> 16) & 1u);
  return (unsigned short)(r >> 16);
}
__device__ __forceinline__ unsigned int pk2(float x, float y) {
  return (unsigned int)f2bs(x) | ((unsigned int)f2bs(y) << 16);
}
__device__ __forceinline__ void stb4(short* p, float4 v) {
  *(unsigned int*)(p)     = pk2(v.x, v.y);
  *(unsigned int*)(p + 2) = pk2(v.z, v.w);
}

// ---------------- k1: conv1 + ReLU + maxpool2, blocks >=512 do weight prep ----------------
__global__ __launch_bounds__(256) void k1_conv1(const float* __restrict__ x,
    const float* __restrict__ w, const float* __restrict__ bias,
    float* __restrict__ h1,
    const float* __restrict__ eqw, float* __restrict__ Wt,
    const float* __restrict__ fcw, short* __restrict__ fcwb) {
  const int n = blockIdx.x, t = threadIdx.x;
  if (n >= 512) {
    if (n < 520) {               // eq_w (d,e,m) -> Wt[m][e][d]
      const int m = n - 512;
      for (int idx = t; idx < 4096; idx += 256) {
        int e = idx >> 6, d = idx & 63;
        Wt[m*4096 + idx] = eqw[d*512 + e*8 + m];
      }
    } else {                     // fc_w f32 -> bf16 (same [e][k] layout)
      int base = (n - 520)*12544 + t;
      for (int q = 0; q < 49; ++q) {
        int idx = base + q*256;
        fcwb[idx] = (short)f2bs(fcw[idx]);
      }
    }
    return;
  }
  __shared__ float si[30*30];
  __shared__ float sw[32*9];
  __shared__ float sb[32];
  for (int idx = t; idx < 900; idx += 256) si[idx] = 0.f;
  for (int idx = t; idx < 288; idx += 256) sw[idx] = w[idx];
  if (t < 32) sb[t] = bias[t];
  __syncthreads();
  for (int idx = t; idx < 784; idx += 256) {
    int y = idx / 28, xx = idx - y*28;
    si[(y+1)*30 + xx + 1] = x[n*784 + idx];
  }
  __syncthreads();
  for (int item = t; item < 6272; item += 256) {
    int c = item / 196, rem = item - c*196;
    int py = rem / 14, px = rem - py*14;
    float pt[4][4];
#pragma unroll
    for (int r = 0; r < 4; ++r)
#pragma unroll
      for (int q = 0; q < 4; ++q)
        pt[r][q] = si[(2*py + r)*30 + 2*px + q];
    const float* wc = &sw[c*9];
    float w0=wc[0], w1=wc[1], w2=wc[2], w3=wc[3], w4=wc[4], w5=wc[5], w6=wc[6], w7=wc[7], w8=wc[8];
    float bb = sb[c];
    float best = 0.f;
#pragma unroll
    for (int a = 0; a < 2; ++a)
#pragma unroll
      for (int b2 = 0; b2 < 2; ++b2) {
        float v = bb
          + w0*pt[a+0][b2+0] + w1*pt[a+0][b2+1] + w2*pt[a+0][b2+2]
          + w3*pt[a+1][b2+0] + w4*pt[a+1][b2+1] + w5*pt[a+1][b2+2]
          + w6*pt[a+2][b2+0] + w7*pt[a+2][b2+1] + w8*pt[a+2][b2+2];
        best = fmaxf(best, v);
      }
    h1[n*6272 + item] = best;
  }
}

// ---------------- k2: conv2 via bf16 MFMA implicit-GEMM, writes h2 as bf16 ----------------
__global__ __launch_bounds__(256, 2) void k2_mfma(const float* __restrict__ h1,
    const float* __restrict__ w, const float* __restrict__ bias,
    short* __restrict__ h2b) {
  __shared__ __align__(16) short inT[16*18*40];  // [yy][xx][cin stride 40]
  const int n = blockIdx.x, t = threadIdx.x;
  const int wv = t >> 6, l = t & 63, quad = l >> 4, col = l & 15;

  unsigned int* zp = (unsigned int*)inT;
  for (int idx = t; idx < 16*18*20; idx += 256) zp[idx] = 0u;

  const int c_out = wv*16 + col;
  float w72[72];
  {
    const float4* src = (const float4*)(w + c_out*288 + quad*72);
#pragma unroll
    for (int q = 0; q < 18; ++q) {
      float4 v = src[q];
      w72[q*4+0] = v.x; w72[q*4+1] = v.y; w72[q*4+2] = v.z; w72[q*4+3] = v.w;
    }
  }
  union SU { short8 v; unsigned int u[4]; };
  short8 Bq[9];
#pragma unroll
  for (int dd = 0; dd < 9; ++dd) {
    SU b;
#pragma unroll
    for (int q = 0; q < 4; ++q)
      b.u[q] = pk2(w72[(2*q)*9 + dd], w72[(2*q+1)*9 + dd]);
    Bq[dd] = b.v;
  }
  const float bb = bias[c_out];
  __syncthreads();

  for (int idx = t; idx < 6272; idx += 256) {
    int c = idx / 196, rem = idx - c*196, y = rem / 14, x = rem - y*14;
    inT[(y+1)*720 + (x+1)*40 + c] = (short)f2bs(h1[n*6272 + idx]);
  }
  __syncthreads();

  for (int p = 0; p < 7; ++p) {
    short8 Ar[4][3];
#pragma unroll
    for (int rr = 0; rr < 4; ++rr)
#pragma unroll
      for (int dx = 0; dx < 3; ++dx)
        Ar[rr][dx] = *(const short8*)&inT[(2*p + rr)*720 + (col + dx)*40 + quad*8];
    f32x4 a0 = {0.f,0.f,0.f,0.f}, a1 = {0.f,0.f,0.f,0.f};
#pragma unroll
    for (int dy = 0; dy < 3; ++dy)
#pragma unroll
      for (int dx = 0; dx < 3; ++dx) {
        a0 = mfma_bf16(Ar[dy][dx],     Bq[dy*3 + dx], a0);
        a1 = mfma_bf16(Ar[dy + 1][dx], Bq[dy*3 + dx], a1);
      }
#pragma unroll
    for (int a = 0; a < 2; ++a) {
      int px = quad*2 + a;
      if (px < 7) {
        float m0 = fmaxf(fmaxf(a0[2*a], a0[2*a + 1]), fmaxf(a1[2*a], a1[2*a + 1]));
        h2b[n*3136 + c_out*49 + p*7 + px] = (short)f2bs(fmaxf(m0 + bb, 0.f));
      }
    }
  }
}

// ---------------- k3: FC 3136->64 split-K(14) bf16 MFMA -> f32 partials ----------------
// grid (16 m-blocks, 14 k-chunks); wave w: m-tile (w&1), n-tile pair (w>>1)
__global__ __launch_bounds__(256) void k3_mfma(const short* __restrict__ h2b,
    const short* __restrict__ fcwb, float* __restrict__ part) {
  const int blk = blockIdx.x, kp = blockIdx.y, t = threadIdx.x;
  const int w = t >> 6, l = t & 63, quad = l >> 4, col = l & 15;
  const int mt = w & 1, nh = w >> 1;
  const int img = blk*32 + mt*16 + col;
  const short* Ap = h2b + img*3136 + kp*224 + quad*8;
  const short* B0 = fcwb + (nh*32 + col)*3136 + kp*224 + quad*8;
  const short* B1 = fcwb + (nh*32 + 16 + col)*3136 + kp*224 + quad*8;
  f32x4 acc0 = {0.f,0.f,0.f,0.f}, acc1 = {0.f,0.f,0.f,0.f};
#pragma unroll
  for (int q = 0; q < 7; ++q) {
    short8 A  = *(const short8*)(Ap + q*32);
    short8 b0 = *(const short8*)(B0 + q*32);
    short8 b1 = *(const short8*)(B1 + q*32);
    acc0 = mfma_bf16(A, b0, acc0);
    acc1 = mfma_bf16(A, b1, acc1);
  }
  const int e0 = nh*32 + col, e1 = e0 + 16;
  const int base = blk*32 + mt*16 + quad*4;
  float* dst = part + kp*32768;
#pragma unroll
  for (int r = 0; r < 4; ++r) {
    dst[(base + r)*64 + e0] = acc0[r];
    dst[(base + r)*64 + e1] = acc1[r];
  }
}

// ---------------- k4: reduce partials + bias + relu -> feat; s, t7c, zero x8 ----------------
__global__ __launch_bounds__(256) void k4_prep(const float* __restrict__ part,
    const float* __restrict__ fb, const float* __restrict__ Wt,
    const float* __restrict__ eqb, float* __restrict__ feat,
    float* __restrict__ s, float* __restrict__ t7c, float* __restrict__ x8) {
  __shared__ __align__(16) float sf[2048];
  __shared__ float ss[64];
  const int b = blockIdx.x, t = threadIdx.x;
  for (int v4 = t; v4 < 512; v4 += 256) {
    float4 a = {0.f, 0.f, 0.f, 0.f};
#pragma unroll
    for (int kp = 0; kp < 14; ++kp) {
      float4 p = *(const float4*)&part[kp*32768 + b*2048 + v4*4];
      a.x += p.x; a.y += p.y; a.z += p.z; a.w += p.w;
    }
    float4 fbv = *(const float4*)&fb[(v4*4) & 63];
    float4 r;
    r.x = fmaxf(a.x + fbv.x, 0.f);
    r.y = fmaxf(a.y + fbv.y, 0.f);
    r.z = fmaxf(a.z + fbv.z, 0.f);
    r.w = fmaxf(a.w + fbv.w, 0.f);
    *(float4*)&sf[v4*4] = r;
    *(float4*)&feat[b*2048 + v4*4] = r;
  }
  __syncthreads();
  if (t < 64) {
    float a = 0.f;
    for (int i = 0; i < 32; ++i) a += sf[i*64 + t];
    a *= (1.f/32.f);
    s[b*64 + t] = a;
    ss[t] = a;
  }
  __syncthreads();
  if (t < 64) {
    const float* W7 = Wt + 7*4096 + t*64;   // [m=7][e=t][d]
    float t7 = 0.f;
    for (int d = 0; d < 64; ++d) {
      float sv = ss[d];
      t7 += sv*sv*sv * W7[d];
    }
    t7c[b*64 + t] = t7 + eqb[t];
    x8[b*64 + t] = 0.f;
  }
}

// ---------------- k5: fused equivariant layer via bf16 MFMA ----------------
__global__ __launch_bounds__(256, 2) void k5_mfma(const float* __restrict__ feat,
    const float* __restrict__ s_, const float* __restrict__ Wt,
    const float* __restrict__ t7c, float* __restrict__ x8) {
  __shared__ __align__(16) float Fm[32*68];
  __shared__ __align__(16) float FI[64];
  __shared__ __align__(16) float SV[64];
  __shared__ __align__(16) float C0[64];
  __shared__ float C0P[128];
  __shared__ float KCf[32*68];
  __shared__ float JCf[32*68];
  __shared__ float RED[256];
  __shared__ __align__(16) short Fb[32*72];
  __shared__ __align__(16) short QPb[64*72];
  __shared__ __align__(16) short G2b[64*72];
  __shared__ __align__(16) short G3b[64*72];

  const int i = blockIdx.x, b = blockIdx.y, t = threadIdx.x;
  const int w = t >> 6, l = t & 63, quad = l >> 4, col = l & 15;

  for (int idx = t; idx < 2048; idx += 256) {
    int r = idx >> 6, d = idx & 63;
    float v = feat[b*2048 + idx];
    Fm[r*68 + d] = v;
    Fb[r*72 + d] = (short)f2bs(v);
  }
  if (t < 64) { FI[t] = feat[b*2048 + i*64 + t]; SV[t] = s_[b*64 + t]; }
  __syncthreads();

  {
    const int e = t >> 2, dbase = (t & 3) * 16;
    const float* W0 = Wt + 0*4096 + e*64;
    const float* W1 = Wt + 1*4096 + e*64;
    const float* W2 = Wt + 2*4096 + e*64;
    const float* W3 = Wt + 3*4096 + e*64;
    const float* W4 = Wt + 4*4096 + e*64;
    const float* W5 = Wt + 5*4096 + e*64;
#pragma unroll
    for (int q = 0; q < 4; ++q) {
      int off = dbase + q*4;
      float4 fi4 = *(const float4*)&FI[off];
      float4 sv4 = *(const float4*)&SV[off];
      float4 w0 = *(const float4*)&W0[off];
      float4 w1 = *(const float4*)&W1[off];
      float4 w2 = *(const float4*)&W2[off];
      float4 w3 = *(const float4*)&W3[off];
      float4 w4 = *(const float4*)&W4[off];
      float4 w5 = *(const float4*)&W5[off];
      float4 qp = fi4*w0 + sv4*w1;
      float4 g2 = sv4*(fi4*w2 + sv4*w4);
      float4 g3 = sv4*(fi4*w3 + sv4*w5);
      stb4(&QPb[e*72 + off], qp);
      stb4(&G2b[e*72 + off], g2);
      stb4(&G3b[e*72 + off], g3);
    }
  }
  if (t < 128) {
    int e = t & 63, dh = t >> 6;
    const float* W6 = Wt + 6*4096 + e*64 + dh*32;
    const float* fip = FI + dh*32;
    const float* svp = SV + dh*32;
    float a = 0.f;
#pragma unroll
    for (int dd = 0; dd < 32; ++dd) {
      float sd = svp[dd];
      a += sd*sd*fip[dd]*W6[dd];
    }
    C0P[dh*64 + e] = a;
  }
  __syncthreads();

  if (w < 2) {
    const short* G = w ? G3b : G2b;
    float* DST = w ? JCf : KCf;
    short8 Bf[4][2];
#pragma unroll
    for (int n = 0; n < 4; ++n)
#pragma unroll
      for (int s2 = 0; s2 < 2; ++s2)
        Bf[n][s2] = *(const short8*)&G[(n*16 + col)*72 + s2*32 + quad*8];
#pragma unroll
    for (int m = 0; m < 2; ++m) {
      short8 A0 = *(const short8*)&Fb[(m*16 + col)*72 + quad*8];
      short8 A1 = *(const short8*)&Fb[(m*16 + col)*72 + 32 + quad*8];
#pragma unroll
      for (int n = 0; n < 4; ++n) {
        f32x4 z = {0.f, 0.f, 0.f, 0.f};
        f32x4 ac = mfma_bf16(A1, Bf[n][1], mfma_bf16(A0, Bf[n][0], z));
#pragma unroll
        for (int r = 0; r < 4; ++r)
          DST[(m*16 + quad*4 + r)*68 + n*16 + col] = ac[r];
      }
    }
  } else if (w == 2) {
    C0[l] = C0P[l] + C0P[64 + l] + t7c[b*64 + l];
  }
  __syncthreads();

  float c0v[4];
#pragma unroll
  for (int n = 0; n < 4; ++n) c0v[n] = C0[n*16 + col];
  float jcq[8][4];
#pragma unroll
  for (int jj = 0; jj < 8; ++jj)
#pragma unroll
    for (int n = 0; n < 4; ++n)
      jcq[jj][n] = JCf[(w*8 + jj)*68 + n*16 + col] + c0v[n];
  float kcv[2][4][4];
#pragma unroll
  for (int kb2 = 0; kb2 < 2; ++kb2)
#pragma unroll
    for (int r = 0; r < 4; ++r)
#pragma unroll
      for (int n = 0; n < 4; ++n)
        kcv[kb2][r][n] = KCf[(kb2*16 + quad*4 + r)*68 + n*16 + col];
  short8 Bq[4][2];
#pragma unroll
  for (int n = 0; n < 4; ++n)
#pragma unroll
    for (int s2 = 0; s2 < 2; ++s2)
      Bq[n][s2] = *(const short8*)&QPb[(n*16 + col)*72 + s2*32 + quad*8];

  float sum[4] = {0.f, 0.f, 0.f, 0.f};
  union SU { short8 v; unsigned int u[4]; };

#pragma unroll
  for (int mi = 0; mi < 16; ++mi) {
    const int jj = mi >> 1, kb2 = mi & 1;
    const float* fj = &Fm[(w*8 + jj)*68 + quad*8];
    const float* fk = &Fm[(kb2*16 + col)*68 + quad*8];
    float4 ja0 = *(const float4*)(fj);
    float4 ja1 = *(const float4*)(fj + 4);
    float4 jb0 = *(const float4*)(fj + 32);
    float4 jb1 = *(const float4*)(fj + 36);
    float4 ka0 = *(const float4*)(fk);
    float4 ka1 = *(const float4*)(fk + 4);
    float4 kb0 = *(const float4*)(fk + 32);
    float4 kb1 = *(const float4*)(fk + 36);
    SU A0, A1;
    A0.u[0] = pk2(ja0.x*ka0.x, ja0.y*ka0.y);
    A0.u[1] = pk2(ja0.z*ka0.z, ja0.w*ka0.w);
    A0.u[2] = pk2(ja1.x*ka1.x, ja1.y*ka1.y);
    A0.u[3] = pk2(ja1.z*ka1.z, ja1.w*ka1.w);
    A1.u[0] = pk2(jb0.x*kb0.x, jb0.y*kb0.y);
    A1.u[1] = pk2(jb0.z*kb0.z, jb0.w*kb0.w);
    A1.u[2] = pk2(jb1.x*kb1.x, jb1.y*kb1.y);
    A1.u[3] = pk2(jb1.z*kb1.z, jb1.w*kb1.w);
    f32x4 ac[4];
#pragma unroll
    for (int n = 0; n < 4; ++n) {
      f32x4 z = {0.f, 0.f, 0.f, 0.f};
      ac[n] = mfma_bf16(A1.v, Bq[n][1], mfma_bf16(A0.v, Bq[n][0], z));
    }
#pragma unroll
    for (int n = 0; n < 4; ++n)
#pragma unroll
      for (int r = 0; r < 4; ++r) {
        float v = ac[n][r] + kcv[kb2][r][n] + jcq[jj][n];
        sum[n] += fmaxf(v, 0.f);
      }
  }

#pragma unroll
  for (int n = 0; n < 4; ++n) {
    float v = sum[n];
    v += __shfl_xor(v, 16, 64);
    v += __shfl_xor(v, 32, 64);
    if (l < 16) RED[w*64 + n*16 + l] = v;
  }
  __syncthreads();
  if (t < 64) {
    float tot = RED[t] + RED[64 + t] + RED[128 + t] + RED[192 + t];
    atomicAdd(&x8[b*64 + t], tot);
  }
}

// ---------------- k6: x9 = relu(x8/K^3); out = x9 @ out_w.T + out_b ----------------
__global__ __launch_bounds__(64) void k6_out(const float* __restrict__ x8,
    const float* __restrict__ ow, const float* __restrict__ ob,
    float* __restrict__ out) {
  const int bb = blockIdx.x, t = threadIdx.x;
  float v = fmaxf(x8[bb*64 + t] * (1.f/32768.f), 0.f) * ow[t];
#pragma unroll
  for (int off = 32; off > 0; off >>= 1) v += __shfl_down(v, off, 64);
  if (t == 0) out[bb] = v + ob[0];
}

extern "C" void kernel_launch(void* const* d_in, const int* in_sizes, int n_in,
                              void* d_out, int out_size, void* d_ws, size_t ws_size,
                              hipStream_t stream) {
  const float* x   = (const float*)d_in[0];
  const float* c1w = (const float*)d_in[1];
  const float* c1b = (const float*)d_in[2];
  const float* c2w = (const float*)d_in[3];
  const float* c2b = (const float*)d_in[4];
  const float* fcw = (const float*)d_in[5];
  const float* fcb = (const float*)d_in[6];
  const float* eqw = (const float*)d_in[7];
  const float* eqb = (const float*)d_in[8];
  const float* ow  = (const float*)d_in[9];
  const float* ob  = (const float*)d_in[10];
  float* out = (float*)d_out;

  float* ws   = (float*)d_ws;
  float* h1   = ws;                       // 512*6272 f32
  short* h2b  = (short*)(h1 + 512*6272);  // 512*3136 bf16
  float* feat = (float*)(h2b + 512*3136); // 512*64 f32
  float* s    = feat + 512*64;            // 16*64
  float* t7c  = s + 1024;
  float* x8   = t7c + 1024;
  float* Wt   = x8 + 1024;                // 8*64*64
  short* fcwb = (short*)(Wt + 32768);     // 64*3136 bf16
  float* part = (float*)(fcwb + 200704);  // 14*512*64 f32

  hipLaunchKernelGGL(k1_conv1, dim3(536), dim3(256), 0, stream,
                     x, c1w, c1b, h1, eqw, Wt, fcw, fcwb);
  hipLaunchKernelGGL(k2_mfma,  dim3(512), dim3(256), 0, stream, h1, c2w, c2b, h2b);
  hipLaunchKernelGGL(k3_mfma,  dim3(16, 14), dim3(256), 0, stream, h2b, fcwb, part);
  hipLaunchKernelGGL(k4_prep,  dim3(16),  dim3(256), 0, stream,
                     part, fcb, Wt, eqb, feat, s, t7c, x8);
  hipLaunchKernelGGL(k5_mfma,  dim3(32, 16), dim3(256), 0, stream, feat, s, Wt, t7c, x8);
  hipLaunchKernelGGL(k6_out,   dim3(16),  dim3(64),  0, stream, x8, ow, ob, out);
}

// Round 6
// 131.511 us; speedup vs baseline: 1.3037x; 1.0455x over previous
//
#include <hip/hip_runtime.h>
#include <hip/hip_bf16.h>

// B=16, K=32, H=W=28, HID=OUT=64, NOPS=8
// ws layout: h1b bf16[512*6272] ([img][pos][cin]) | h2b bf16[512*3136] | feat f32[512*64]
//            | s[16*64] | t7c[16*64] | x8[16*64] | Wt f32[8*64*64] ([m][e][d])
//            | fcwb bf16[64*3136] | part f32[14*512*64]

typedef __attribute__((ext_vector_type(8))) short short8;
typedef __attribute__((ext_vector_type(4))) float f32x4;

__device__ __forceinline__ f32x4 mfma_bf16(short8 a, short8 b, f32x4 c) {
  return __builtin_amdgcn_mfma_f32_16x16x32_bf16(a, b, c, 0, 0, 0);
}

// float -> bf16 bits, round-to-nearest-even (finite inputs only)
__device__ __forceinline__ unsigned short f2bs(float f) {
  unsigned int u = __float_as_uint(f);
  unsigned int r = u + 0x7fffu + ((u >> 16) & 1u);
  return (unsigned short)(r >> 16);
}
// packed 2xfp32 -> 2xbf16 (v_cvt_pk_bf16_f32 on gfx950)
__device__ __forceinline__ unsigned int pk2(float x, float y) {
  union { __hip_bfloat162 h; unsigned int u; } cv;
  cv.h = __float22bfloat162_rn(make_float2(x, y));
  return cv.u;
}
__device__ __forceinline__ void stb4(short* p, float4 v) {
  *(unsigned int*)(p)     = pk2(v.x, v.y);
  *(unsigned int*)(p + 2) = pk2(v.z, v.w);
}

// ---------------- k1: conv1 + ReLU + maxpool2 -> h1b bf16 [pos][cin]; prep blocks >=512 ----------------
__global__ __launch_bounds__(256) void k1_conv1(const float* __restrict__ x,
    const float* __restrict__ w, const float* __restrict__ bias,
    short* __restrict__ h1b,
    const float* __restrict__ eqw, float* __restrict__ Wt,
    const float* __restrict__ fcw, short* __restrict__ fcwb) {
  const int n = blockIdx.x, t = threadIdx.x;
  if (n >= 512) {
    if (n < 520) {               // eq_w (d,e,m) -> Wt[m][e][d]
      const int m = n - 512;
      for (int idx = t; idx < 4096; idx += 256) {
        int e = idx >> 6, d = idx & 63;
        Wt[m*4096 + idx] = eqw[d*512 + e*8 + m];
      }
    } else {                     // fc_w f32 -> bf16 (same [e][k] layout)
      int base = (n - 520)*12544 + t;
      for (int q = 0; q < 49; ++q) {
        int idx = base + q*256;
        fcwb[idx] = (short)f2bs(fcw[idx]);
      }
    }
    return;
  }
  __shared__ float si[30*30];
  __shared__ float sw[32*9];
  __shared__ float sb[32];
  for (int idx = t; idx < 900; idx += 256) si[idx] = 0.f;
  for (int idx = t; idx < 288; idx += 256) sw[idx] = w[idx];
  if (t < 32) sb[t] = bias[t];
  __syncthreads();
  for (int idx = t; idx < 784; idx += 256) {
    int y = idx / 28, xx = idx - y*28;
    si[(y+1)*30 + xx + 1] = x[n*784 + idx];
  }
  __syncthreads();
  // item = pos*32 + c  (writes coalesced; si reads broadcast across 32 lanes)
  for (int idx = t; idx < 6272; idx += 256) {
    int pos = idx >> 5, c = idx & 31;
    int py = pos / 14, px = pos - py*14;
    float pt[4][4];
#pragma unroll
    for (int r = 0; r < 4; ++r)
#pragma unroll
      for (int q = 0; q < 4; ++q)
        pt[r][q] = si[(2*py + r)*30 + 2*px + q];
    const float* wc = &sw[c*9];
    float w0=wc[0], w1=wc[1], w2=wc[2], w3=wc[3], w4=wc[4], w5=wc[5], w6=wc[6], w7=wc[7], w8=wc[8];
    float bb = sb[c];
    float best = 0.f;
#pragma unroll
    for (int a = 0; a < 2; ++a)
#pragma unroll
      for (int b2 = 0; b2 < 2; ++b2) {
        float v = bb
          + w0*pt[a+0][b2+0] + w1*pt[a+0][b2+1] + w2*pt[a+0][b2+2]
          + w3*pt[a+1][b2+0] + w4*pt[a+1][b2+1] + w5*pt[a+1][b2+2]
          + w6*pt[a+2][b2+0] + w7*pt[a+2][b2+1] + w8*pt[a+2][b2+2];
        best = fmaxf(best, v);
      }
    h1b[n*6272 + idx] = (short)f2bs(best);
  }
}

// ---------------- k2: conv2 via bf16 MFMA implicit-GEMM, writes h2 as bf16 ----------------
__global__ __launch_bounds__(256, 2) void k2_mfma(const short* __restrict__ h1b,
    const float* __restrict__ w, const float* __restrict__ bias,
    short* __restrict__ h2b) {
  __shared__ __align__(16) short inT[16*18*40];  // [yy][xx][cin stride 40]
  const int n = blockIdx.x, t = threadIdx.x;
  const int wv = t >> 6, l = t & 63, quad = l >> 4, col = l & 15;

  unsigned int* zp = (unsigned int*)inT;
  for (int idx = t; idx < 16*18*20; idx += 256) zp[idx] = 0u;

  const int c_out = wv*16 + col;
  float w72[72];
  {
    const float4* src = (const float4*)(w + c_out*288 + quad*72);
#pragma unroll
    for (int q = 0; q < 18; ++q) {
      float4 v = src[q];
      w72[q*4+0] = v.x; w72[q*4+1] = v.y; w72[q*4+2] = v.z; w72[q*4+3] = v.w;
    }
  }
  union SU { short8 v; unsigned int u[4]; };
  short8 Bq[9];
#pragma unroll
  for (int dd = 0; dd < 9; ++dd) {
    SU b;
#pragma unroll
    for (int q = 0; q < 4; ++q)
      b.u[q] = pk2(w72[(2*q)*9 + dd], w72[(2*q+1)*9 + dd]);
    Bq[dd] = b.v;
  }
  const float bb = bias[c_out];
  __syncthreads();

  // stage h1b -> inT (pure uint4 copy; h1b already bf16 [pos][cin])
  {
    const uint4* src = (const uint4*)(h1b + n*6272);
    for (int idx = t; idx < 784; idx += 256) {
      uint4 v = src[idx];
      int pos = idx >> 2, cb = (idx & 3) * 8;
      int y = pos / 14, xx = pos - y*14;
      *(uint4*)&inT[(y+1)*720 + (xx+1)*40 + cb] = v;
    }
  }
  __syncthreads();

  for (int p = 0; p < 7; ++p) {
    short8 Ar[4][3];
#pragma unroll
    for (int rr = 0; rr < 4; ++rr)
#pragma unroll
      for (int dx = 0; dx < 3; ++dx)
        Ar[rr][dx] = *(const short8*)&inT[(2*p + rr)*720 + (col + dx)*40 + quad*8];
    f32x4 a0 = {0.f,0.f,0.f,0.f}, a1 = {0.f,0.f,0.f,0.f};
#pragma unroll
    for (int dy = 0; dy < 3; ++dy)
#pragma unroll
      for (int dx = 0; dx < 3; ++dx) {
        a0 = mfma_bf16(Ar[dy][dx],     Bq[dy*3 + dx], a0);
        a1 = mfma_bf16(Ar[dy + 1][dx], Bq[dy*3 + dx], a1);
      }
#pragma unroll
    for (int a = 0; a < 2; ++a) {
      int px = quad*2 + a;
      if (px < 7) {
        float m0 = fmaxf(fmaxf(a0[2*a], a0[2*a + 1]), fmaxf(a1[2*a], a1[2*a + 1]));
        h2b[n*3136 + c_out*49 + p*7 + px] = (short)f2bs(fmaxf(m0 + bb, 0.f));
      }
    }
  }
}

// ---------------- k3: FC 3136->64 split-K(14) bf16 MFMA -> f32 partials ----------------
__global__ __launch_bounds__(256) void k3_mfma(const short* __restrict__ h2b,
    const short* __restrict__ fcwb, float* __restrict__ part) {
  const int blk = blockIdx.x, kp = blockIdx.y, t = threadIdx.x;
  const int w = t >> 6, l = t & 63, quad = l >> 4, col = l & 15;
  const int mt = w & 1, nh = w >> 1;
  const int img = blk*32 + mt*16 + col;
  const short* Ap = h2b + img*3136 + kp*224 + quad*8;
  const short* B0 = fcwb + (nh*32 + col)*3136 + kp*224 + quad*8;
  const short* B1 = fcwb + (nh*32 + 16 + col)*3136 + kp*224 + quad*8;
  f32x4 acc0 = {0.f,0.f,0.f,0.f}, acc1 = {0.f,0.f,0.f,0.f};
#pragma unroll
  for (int q = 0; q < 7; ++q) {
    short8 A  = *(const short8*)(Ap + q*32);
    short8 b0 = *(const short8*)(B0 + q*32);
    short8 b1 = *(const short8*)(B1 + q*32);
    acc0 = mfma_bf16(A, b0, acc0);
    acc1 = mfma_bf16(A, b1, acc1);
  }
  const int e0 = nh*32 + col, e1 = e0 + 16;
  const int base = blk*32 + mt*16 + quad*4;
  float* dst = part + kp*32768;
#pragma unroll
  for (int r = 0; r < 4; ++r) {
    dst[(base + r)*64 + e0] = acc0[r];
    dst[(base + r)*64 + e1] = acc1[r];
  }
}

// ---------------- k4: reduce partials + bias + relu -> feat; s, t7c, zero x8 ----------------
__global__ __launch_bounds__(256) void k4_prep(const float* __restrict__ part,
    const float* __restrict__ fb, const float* __restrict__ Wt,
    const float* __restrict__ eqb, float* __restrict__ feat,
    float* __restrict__ s, float* __restrict__ t7c, float* __restrict__ x8) {
  __shared__ __align__(16) float sf[2048];
  __shared__ float ss[64];
  const int b = blockIdx.x, t = threadIdx.x;
  for (int v4 = t; v4 < 512; v4 += 256) {
    float4 a = {0.f, 0.f, 0.f, 0.f};
#pragma unroll
    for (int kp = 0; kp < 14; ++kp) {
      float4 p = *(const float4*)&part[kp*32768 + b*2048 + v4*4];
      a.x += p.x; a.y += p.y; a.z += p.z; a.w += p.w;
    }
    float4 fbv = *(const float4*)&fb[(v4*4) & 63];
    float4 r;
    r.x = fmaxf(a.x + fbv.x, 0.f);
    r.y = fmaxf(a.y + fbv.y, 0.f);
    r.z = fmaxf(a.z + fbv.z, 0.f);
    r.w = fmaxf(a.w + fbv.w, 0.f);
    *(float4*)&sf[v4*4] = r;
    *(float4*)&feat[b*2048 + v4*4] = r;
  }
  __syncthreads();
  if (t < 64) {
    float a = 0.f;
    for (int i = 0; i < 32; ++i) a += sf[i*64 + t];
    a *= (1.f/32.f);
    s[b*64 + t] = a;
    ss[t] = a;
  }
  __syncthreads();
  if (t < 64) {
    const float* W7 = Wt + 7*4096 + t*64;   // [m=7][e=t][d]
    float t7 = 0.f;
    for (int d = 0; d < 64; ++d) {
      float sv = ss[d];
      t7 += sv*sv*sv * W7[d];
    }
    t7c[b*64 + t] = t7 + eqb[t];
    x8[b*64 + t] = 0.f;
  }
}

// ---------------- k5: fused equivariant layer via bf16 MFMA ----------------
__global__ __launch_bounds__(256, 2) void k5_mfma(const float* __restrict__ feat,
    const float* __restrict__ s_, const float* __restrict__ Wt,
    const float* __restrict__ t7c, float* __restrict__ x8) {
  __shared__ __align__(16) float Fm[32*68];
  __shared__ __align__(16) float FI[64];
  __shared__ __align__(16) float SV[64];
  __shared__ __align__(16) float C0[64];
  __shared__ float C0P[128];
  __shared__ float KCf[32*68];
  __shared__ float JCf[32*68];
  __shared__ float RED[256];
  __shared__ __align__(16) short Fb[32*72];
  __shared__ __align__(16) short QPb[64*72];
  __shared__ __align__(16) short G2b[64*72];
  __shared__ __align__(16) short G3b[64*72];

  const int i = blockIdx.x, b = blockIdx.y, t = threadIdx.x;
  const int w = t >> 6, l = t & 63, quad = l >> 4, col = l & 15;

  for (int idx = t; idx < 2048; idx += 256) {
    int r = idx >> 6, d = idx & 63;
    float v = feat[b*2048 + idx];
    Fm[r*68 + d] = v;
    Fb[r*72 + d] = (short)f2bs(v);
  }
  if (t < 64) { FI[t] = feat[b*2048 + i*64 + t]; SV[t] = s_[b*64 + t]; }
  __syncthreads();

  {
    const int e = t >> 2, dbase = (t & 3) * 16;
    const float* W0 = Wt + 0*4096 + e*64;
    const float* W1 = Wt + 1*4096 + e*64;
    const float* W2 = Wt + 2*4096 + e*64;
    const float* W3 = Wt + 3*4096 + e*64;
    const float* W4 = Wt + 4*4096 + e*64;
    const float* W5 = Wt + 5*4096 + e*64;
#pragma unroll
    for (int q = 0; q < 4; ++q) {
      int off = dbase + q*4;
      float4 fi4 = *(const float4*)&FI[off];
      float4 sv4 = *(const float4*)&SV[off];
      float4 w0 = *(const float4*)&W0[off];
      float4 w1 = *(const float4*)&W1[off];
      float4 w2 = *(const float4*)&W2[off];
      float4 w3 = *(const float4*)&W3[off];
      float4 w4 = *(const float4*)&W4[off];
      float4 w5 = *(const float4*)&W5[off];
      float4 qp = fi4*w0 + sv4*w1;
      float4 g2 = sv4*(fi4*w2 + sv4*w4);
      float4 g3 = sv4*(fi4*w3 + sv4*w5);
      stb4(&QPb[e*72 + off], qp);
      stb4(&G2b[e*72 + off], g2);
      stb4(&G3b[e*72 + off], g3);
    }
  }
  if (t < 128) {
    int e = t & 63, dh = t >> 6;
    const float* W6 = Wt + 6*4096 + e*64 + dh*32;
    const float* fip = FI + dh*32;
    const float* svp = SV + dh*32;
    float a = 0.f;
#pragma unroll
    for (int dd = 0; dd < 32; ++dd) {
      float sd = svp[dd];
      a += sd*sd*fip[dd]*W6[dd];
    }
    C0P[dh*64 + e] = a;
  }
  __syncthreads();

  if (w < 2) {
    const short* G = w ? G3b : G2b;
    float* DST = w ? JCf : KCf;
    short8 Bf[4][2];
#pragma unroll
    for (int n = 0; n < 4; ++n)
#pragma unroll
      for (int s2 = 0; s2 < 2; ++s2)
        Bf[n][s2] = *(const short8*)&G[(n*16 + col)*72 + s2*32 + quad*8];
#pragma unroll
    for (int m = 0; m < 2; ++m) {
      short8 A0 = *(const short8*)&Fb[(m*16 + col)*72 + quad*8];
      short8 A1 = *(const short8*)&Fb[(m*16 + col)*72 + 32 + quad*8];
#pragma unroll
      for (int n = 0; n < 4; ++n) {
        f32x4 z = {0.f, 0.f, 0.f, 0.f};
        f32x4 ac = mfma_bf16(A1, Bf[n][1], mfma_bf16(A0, Bf[n][0], z));
#pragma unroll
        for (int r = 0; r < 4; ++r)
          DST[(m*16 + quad*4 + r)*68 + n*16 + col] = ac[r];
      }
    }
  } else if (w == 2) {
    C0[l] = C0P[l] + C0P[64 + l] + t7c[b*64 + l];
  }
  __syncthreads();

  float c0v[4];
#pragma unroll
  for (int n = 0; n < 4; ++n) c0v[n] = C0[n*16 + col];
  float jcq[8][4];
#pragma unroll
  for (int jj = 0; jj < 8; ++jj)
#pragma unroll
    for (int n = 0; n < 4; ++n)
      jcq[jj][n] = JCf[(w*8 + jj)*68 + n*16 + col] + c0v[n];
  float kcv[2][4][4];
#pragma unroll
  for (int kb2 = 0; kb2 < 2; ++kb2)
#pragma unroll
    for (int r = 0; r < 4; ++r)
#pragma unroll
      for (int n = 0; n < 4; ++n)
        kcv[kb2][r][n] = KCf[(kb2*16 + quad*4 + r)*68 + n*16 + col];
  short8 Bq[4][2];
#pragma unroll
  for (int n = 0; n < 4; ++n)
#pragma unroll
    for (int s2 = 0; s2 < 2; ++s2)
      Bq[n][s2] = *(const short8*)&QPb[(n*16 + col)*72 + s2*32 + quad*8];

  // hoist fk fragments: only 2 variants (kb2) across the whole loop
  float4 fkv[2][4];
#pragma unroll
  for (int kb2 = 0; kb2 < 2; ++kb2) {
    const float* fk = &Fm[(kb2*16 + col)*68 + quad*8];
    fkv[kb2][0] = *(const float4*)(fk);
    fkv[kb2][1] = *(const float4*)(fk + 4);
    fkv[kb2][2] = *(const float4*)(fk + 32);
    fkv[kb2][3] = *(const float4*)(fk + 36);
  }

  float sum[4] = {0.f, 0.f, 0.f, 0.f};
  union SU { short8 v; unsigned int u[4]; };

#pragma unroll
  for (int jj = 0; jj < 8; ++jj) {
    const float* fj = &Fm[(w*8 + jj)*68 + quad*8];
    float4 j0 = *(const float4*)(fj);
    float4 j1 = *(const float4*)(fj + 4);
    float4 j2 = *(const float4*)(fj + 32);
    float4 j3 = *(const float4*)(fj + 36);
#pragma unroll
    for (int kb2 = 0; kb2 < 2; ++kb2) {
      float4 k0 = fkv[kb2][0], k1 = fkv[kb2][1];
      float4 k2v = fkv[kb2][2], k3v = fkv[kb2][3];
      SU A0, A1;
      A0.u[0] = pk2(j0.x*k0.x, j0.y*k0.y);
      A0.u[1] = pk2(j0.z*k0.z, j0.w*k0.w);
      A0.u[2] = pk2(j1.x*k1.x, j1.y*k1.y);
      A0.u[3] = pk2(j1.z*k1.z, j1.w*k1.w);
      A1.u[0] = pk2(j2.x*k2v.x, j2.y*k2v.y);
      A1.u[1] = pk2(j2.z*k2v.z, j2.w*k2v.w);
      A1.u[2] = pk2(j3.x*k3v.x, j3.y*k3v.y);
      A1.u[3] = pk2(j3.z*k3v.z, j3.w*k3v.w);
      f32x4 ac[4];
#pragma unroll
      for (int n = 0; n < 4; ++n) {
        f32x4 z = {0.f, 0.f, 0.f, 0.f};
        ac[n] = mfma_bf16(A1.v, Bq[n][1], mfma_bf16(A0.v, Bq[n][0], z));
      }
#pragma unroll
      for (int n = 0; n < 4; ++n)
#pragma unroll
        for (int r = 0; r < 4; ++r) {
          float v = ac[n][r] + kcv[kb2][r][n] + jcq[jj][n];
          sum[n] += fmaxf(v, 0.f);
        }
    }
  }

#pragma unroll
  for (int n = 0; n < 4; ++n) {
    float v = sum[n];
    v += __shfl_xor(v, 16, 64);
    v += __shfl_xor(v, 32, 64);
    if (l < 16) RED[w*64 + n*16 + l] = v;
  }
  __syncthreads();
  if (t < 64) {
    float tot = RED[t] + RED[64 + t] + RED[128 + t] + RED[192 + t];
    atomicAdd(&x8[b*64 + t], tot);
  }
}

// ---------------- k6: x9 = relu(x8/K^3); out = x9 @ out_w.T + out_b ----------------
__global__ __launch_bounds__(64) void k6_out(const float* __restrict__ x8,
    const float* __restrict__ ow, const float* __restrict__ ob,
    float* __restrict__ out) {
  const int bb = blockIdx.x, t = threadIdx.x;
  float v = fmaxf(x8[bb*64 + t] * (1.f/32768.f), 0.f) * ow[t];
#pragma unroll
  for (int off = 32; off > 0; off >>= 1) v += __shfl_down(v, off, 64);
  if (t == 0) out[bb] = v + ob[0];
}

extern "C" void kernel_launch(void* const* d_in, const int* in_sizes, int n_in,
                              void* d_out, int out_size, void* d_ws, size_t ws_size,
                              hipStream_t stream) {
  const float* x   = (const float*)d_in[0];
  const float* c1w = (const float*)d_in[1];
  const float* c1b = (const float*)d_in[2];
  const float* c2w = (const float*)d_in[3];
  const float* c2b = (const float*)d_in[4];
  const float* fcw = (const float*)d_in[5];
  const float* fcb = (const float*)d_in[6];
  const float* eqw = (const float*)d_in[7];
  const float* eqb = (const float*)d_in[8];
  const float* ow  = (const float*)d_in[9];
  const float* ob  = (const float*)d_in[10];
  float* out = (float*)d_out;

  short* h1b  = (short*)d_ws;             // 512*6272 bf16 [img][pos][cin]
  short* h2b  = h1b + 512*6272;           // 512*3136 bf16
  float* feat = (float*)(h2b + 512*3136); // 512*64 f32
  float* s    = feat + 512*64;            // 16*64
  float* t7c  = s + 1024;
  float* x8   = t7c + 1024;
  float* Wt   = x8 + 1024;                // 8*64*64
  short* fcwb = (short*)(Wt + 32768);     // 64*3136 bf16
  float* part = (float*)(fcwb + 200704);  // 14*512*64 f32

  hipLaunchKernelGGL(k1_conv1, dim3(536), dim3(256), 0, stream,
                     x, c1w, c1b, h1b, eqw, Wt, fcw, fcwb);
  hipLaunchKernelGGL(k2_mfma,  dim3(512), dim3(256), 0, stream, h1b, c2w, c2b, h2b);
  hipLaunchKernelGGL(k3_mfma,  dim3(16, 14), dim3(256), 0, stream, h2b, fcwb, part);
  hipLaunchKernelGGL(k4_prep,  dim3(16),  dim3(256), 0, stream,
                     part, fcb, Wt, eqb, feat, s, t7c, x8);
  hipLaunchKernelGGL(k5_mfma,  dim3(32, 16), dim3(256), 0, stream, feat, s, Wt, t7c, x8);
  hipLaunchKernelGGL(k6_out,   dim3(16),  dim3(64),  0, stream, x8, ow, ob, out);
}